// Round 10
// baseline (434.393 us; speedup 1.0000x reference)
//
#include <hip/hip_runtime.h>
#include <cstdint>

using u64 = unsigned long long;
using u32 = unsigned int;

// ---------------------------------------------------------------------------
// Fused prep: BN constants + exact integer thresholds (layers 2-4, packed as
// tf[2*oc]={Tx}, tf[2*oc+1]={flip}) + sign packing of w2..w5.
// ---------------------------------------------------------------------------
struct PrepArgs {
  const float* bng[5]; const float* bnb[5]; const float* bnm[5]; const float* bnv[5];
  float* inv1; float* cc1; float* inv5; float* cc5;
  int* tf[3];
  const float* w[4];
  u64* wp[4]; u64* wz[4];
  u32* flags;
};

__global__ __launch_bounds__(256) void prep_all(PrepArgs a) {
  int i = blockIdx.x * 256 + threadIdx.x;
  if (i < 704) {
    const int off[6] = {0, 64, 192, 320, 512, 704};
    int l = 0;
    while (i >= off[l + 1]) ++l;
    int c = i - off[l];
    float iv = __fdiv_rn(a.bng[l][c], __fsqrt_rn(__fadd_rn(a.bnv[l][c], 1e-5f)));
    float cb = __fsub_rn(a.bnb[l][c], __fmul_rn(a.bnm[l][c], iv));
    if (l == 0) { a.inv1[c] = iv; a.cc1[c] = cb; }
    else if (l == 4) { a.inv5[c] = iv; a.cc5[c] = cb; }
    else {
      auto pred = [&](int v_) {
        return __fadd_rn(__fmul_rn((float)v_, iv), cb) > 0.f;
      };
      int Tx, fl;
      if (iv == 0.f) { Tx = pred(0) ? -100000 : 100000; fl = 0; }
      else if (iv > 0.f) {
        if (pred(-2048)) { Tx = -100000; fl = 0; }
        else if (!pred(2048)) { Tx = 100000; fl = 0; }
        else {
          int lo = -2048, hi = 2048;
          while (hi - lo > 1) { int md = (lo + hi) >> 1; if (pred(md)) hi = md; else lo = md; }
          Tx = hi; fl = 0;   // bit = val >= Tx
        }
      } else {
        if (pred(2048)) { Tx = -100000; fl = -1; }
        else if (!pred(-2048)) { Tx = 100000; fl = -1; }
        else {
          int lo = -2048, hi = 2048;
          while (hi - lo > 1) { int md = (lo + hi) >> 1; if (pred(md)) lo = md; else hi = md; }
          Tx = lo ^ -1; fl = -1;  // bit = val <= lo  <=>  (val^-1) >= (~lo)
        }
      }
      a.tf[l - 1][2 * c] = Tx; a.tf[l - 1][2 * c + 1] = fl;
    }
    return;
  }
  int j = i - 704;
  if (j >= 7488) return;
  const int poff[5] = {0, 1152, 3456, 6912, 7488};
  const int ICt[4] = {64, 128, 128, 192};
  const int Kt[4]  = {9, 9, 9, 1};
  const int Wt[4]  = {1, 2, 2, 3};
  int l = 0;
  while (j >= poff[l + 1]) ++l;
  int idx = j - poff[l];
  int W = Wt[l], K = Kt[l], IC = ICt[l];
  int wi = idx % W;
  int rest = idx / W;
  int t = rest % K;
  int oc = rest / K;
  u64 p = 0, z = 0;
  int icbase = wi * 64;
  int nb = IC - icbase; if (nb > 64) nb = 64;
  const float* w = a.w[l];
  for (int b = 0; b < nb; ++b) {
    float f = w[((size_t)oc * IC + (icbase + b)) * K + t];
    if (f > 0.f) p |= (1ull << b);
    else if (f == 0.f) z |= (1ull << b);
  }
  a.wp[l][idx] = p;
  a.wz[l][idx] = z;
  if (z) atomicOr(a.flags + l, 1u);
}

// ---------------------------------------------------------------------------
// Pad fp32 input into [n][130][136].
// ---------------------------------------------------------------------------
__global__ __launch_bounds__(256) void pad_x(const float* __restrict__ x,
                                             float* __restrict__ xpad) {
  int idx = blockIdx.x * 256 + threadIdx.x;
  int c = idx & 127, r = (idx >> 7) & 127, n = idx >> 14;
  xpad[((size_t)n * 130 + r + 1) * 136 + c + 1] = x[idx];
}

// ---------------------------------------------------------------------------
// conv1, lane = pixel (unchanged, passing).
// ---------------------------------------------------------------------------
__global__ __launch_bounds__(256) void conv1_px(
    const float* __restrict__ xpad, const float* __restrict__ w1, const float* __restrict__ b1,
    const float* __restrict__ inv1, const float* __restrict__ cc1,
    u64* __restrict__ a1p) {
  int tid = threadIdx.x, lane = tid & 63;
  int wv = __builtin_amdgcn_readfirstlane(tid >> 6);
  int widx = blockIdx.x * 4 + wv;       // 8192
  int y = widx & 63, n = widx >> 6;
  const float* base = xpad + ((size_t)n * 130 + 2 * y) * 136 + 2 * lane;
  float A[9];
#pragma unroll
  for (int r = 0; r < 3; ++r)
#pragma unroll
    for (int c = 0; c < 3; ++c)
      A[r * 3 + c] = base[r * 136 + c];

  u32 wlo = 0, whi = 0;
#pragma unroll 2
  for (int ch = 0; ch < 64; ++ch) {
    float acc = 0.f;
#pragma unroll
    for (int t = 0; t < 9; ++t) acc += A[t] * w1[ch * 9 + t];
    float h = __fadd_rn(acc, b1[ch]);
    float bnv = __fadd_rn(__fmul_rn(h, inv1[ch]), cc1[ch]);
    u32 b = bnv > 0.f ? 1u : 0u;
    if (ch < 32) wlo |= b << ch;
    else         whi |= b << (ch - 32);
  }
  u64 word = ((u64)whi << 32) | wlo;
  a1p[((size_t)n * 66 + (y + 1)) * 68 + lane + 1] = word;
}

// ---------------------------------------------------------------------------
// Variant A (baseline, R9 template PXV=1): SMEM uniform weights.
// ---------------------------------------------------------------------------
template <int CINW, int COUT, int STRIDE, int IN_HW, int OUT_HW, int PXV, int NSPLIT,
          int OPAD, bool Z>
__device__ __forceinline__ void bconv_sm_body(
    const u64* __restrict__ ain, const u64* __restrict__ wp, const u64* __restrict__ wz,
    const int* __restrict__ tf, u64* __restrict__ aout, int widx, int lane) {
  constexpr int IPW = IN_HW + 4;
  constexpr int K = 9 * CINW;
  constexpr int NR = STRIDE * (PXV - 1) + 3;
  constexpr int NOC = COUT / NSPLIT;
  constexpr int NCH = NOC / 32;
  constexpr int OW32 = ((COUT + 63) / 64) * 2;
  constexpr int LROW = (OUT_HW == 64) ? 1 : 2;
  constexpr int RPWAVE = PXV * LROW;
  constexpr int RG_PER_N = OUT_HW / RPWAVE;

  int split = widx % NSPLIT;
  int rg = widx / NSPLIT;
  int n = rg / RG_PER_N;
  int yg = rg % RG_PER_N;
  int px = (OUT_HW == 64) ? lane : (lane & 31);
  int y0 = yg * RPWAVE + ((OUT_HW == 64) ? 0 : (lane >> 5) * PXV);

  const u64* base = ain + (((size_t)n * (IN_HW + 2) + STRIDE * y0) * IPW + STRIDE * px) * CINW;
  u64 A[NR * 3 * CINW];
#pragma unroll
  for (int r = 0; r < NR; ++r)
#pragma unroll
    for (int c = 0; c < 3; ++c)
#pragma unroll
      for (int w = 0; w < CINW; ++w)
        A[(r * 3 + c) * CINW + w] = base[((size_t)r * IPW + c) * CINW + w];

  int npa[PXV];
#pragma unroll
  for (int p = 0; p < PXV; ++p) {
    int q = 0;
#pragma unroll
    for (int r = 0; r < 3; ++r)
#pragma unroll
      for (int c = 0; c < 3; ++c)
#pragma unroll
        for (int w = 0; w < CINW; ++w)
          q += __popcll(A[((STRIDE * p + r) * 3 + c) * CINW + w]);
    npa[p] = -q;
  }

  int oc0 = split * NOC;
  u32* out32 = (u32*)aout;
  size_t orow[PXV];
#pragma unroll
  for (int p = 0; p < PXV; ++p) {
    if (OPAD)
      orow[p] = (((size_t)n * (OUT_HW + 2) + (y0 + p + 1)) * (OUT_HW + 4) + px + 1) * OW32;
    else
      orow[p] = (((size_t)n * OUT_HW + (y0 + p)) * OUT_HW + px) * OW32;
  }

#pragma unroll
  for (int ch = 0; ch < NCH; ++ch) {
    u32 acc[PXV];
#pragma unroll
    for (int p = 0; p < PXV; ++p) acc[p] = 0;
#pragma unroll 2
    for (int j = 0; j < 32; ++j) {
      int oc = oc0 + ch * 32 + j;
      const u64* wrow = wp + (size_t)oc * K;
      int Tx = tf[2 * oc], flip = tf[2 * oc + 1];
#pragma unroll
      for (int p = 0; p < PXV; ++p) {
        int s = 0;
#pragma unroll
        for (int r = 0; r < 3; ++r)
#pragma unroll
          for (int c = 0; c < 3; ++c)
#pragma unroll
            for (int w = 0; w < CINW; ++w)
              s += __popcll(A[((STRIDE * p + r) * 3 + c) * CINW + w] &
                            wrow[(r * 3 + c) * CINW + w]);
        int val = (s << 1) + npa[p];
        if (Z) {
          const u64* zr = wz + (size_t)oc * K;
#pragma unroll
          for (int r = 0; r < 3; ++r)
#pragma unroll
            for (int c = 0; c < 3; ++c)
#pragma unroll
              for (int w = 0; w < CINW; ++w)
                val += __popcll(A[((STRIDE * p + r) * 3 + c) * CINW + w] &
                                zr[(r * 3 + c) * CINW + w]);
        }
        int tt = (val ^ flip) - Tx;
        acc[p] |= (((u32)~tt) >> 31) << j;
      }
    }
#pragma unroll
    for (int p = 0; p < PXV; ++p)
      out32[orow[p] + (u32)(oc0 / 32 + ch)] = acc[p];
  }
}

template <int CINW, int COUT, int STRIDE, int IN_HW, int OUT_HW, int PXV, int NSPLIT, int OPAD>
__global__ __launch_bounds__(256) void bconv_sm(
    const u64* __restrict__ ain, const u64* __restrict__ wp, const u64* __restrict__ wz,
    const u32* __restrict__ flag, const int* __restrict__ tf, u64* __restrict__ aout) {
  int tid = threadIdx.x, lane = tid & 63;
  int wv = __builtin_amdgcn_readfirstlane(tid >> 6);
  int widx = blockIdx.x * 4 + wv;
  bool anyz = (*flag != 0u);
  if (anyz)
    bconv_sm_body<CINW, COUT, STRIDE, IN_HW, OUT_HW, PXV, NSPLIT, OPAD, true>(
        ain, wp, wz, tf, aout, widx, lane);
  else
    bconv_sm_body<CINW, COUT, STRIDE, IN_HW, OUT_HW, PXV, NSPLIT, OPAD, false>(
        ain, wp, wz, tf, aout, widx, lane);
}

// ---------------------------------------------------------------------------
// Variant B: VMEM weight stream (opaque-zero VGPR offset -> global_load,
// in-order vmcnt, broadcast from L1) with explicit Wa/Wb ping-pong
// (distance-1 prefetch, all register indices compile-time).
// wp/wz need one PAD ROW past COUT (trailing prefetch); tf needs +2 ints.
// ---------------------------------------------------------------------------
template <int CINW, int COUT, int STRIDE, int IN_HW, int OUT_HW, int NSPLIT, int OPAD, bool Z>
__device__ __forceinline__ void bconv_vm_body(
    const u64* __restrict__ ain, const u64* __restrict__ wp, const u64* __restrict__ wz,
    const int* __restrict__ tf, u64* __restrict__ aout, int widx, int lane, int dz) {
  constexpr int IPW = IN_HW + 4;
  constexpr int K = 9 * CINW;
  constexpr int NOC = COUT / NSPLIT;
  constexpr int NCH = NOC / 32;
  constexpr int OW32 = ((COUT + 63) / 64) * 2;
  constexpr int LROW = (OUT_HW == 64) ? 1 : 2;
  constexpr int RG_PER_N = OUT_HW / LROW;

  int split = widx % NSPLIT;
  int rg = widx / NSPLIT;
  int n = rg / RG_PER_N;
  int yg = rg % RG_PER_N;
  int px = (OUT_HW == 64) ? lane : (lane & 31);
  int y = yg * LROW + ((OUT_HW == 64) ? 0 : (lane >> 5));

  const u64* base = ain + (((size_t)n * (IN_HW + 2) + STRIDE * y) * IPW + STRIDE * px) * CINW;
  u64 A[K];
#pragma unroll
  for (int r = 0; r < 3; ++r)
#pragma unroll
    for (int c = 0; c < 3; ++c)
#pragma unroll
      for (int w = 0; w < CINW; ++w)
        A[(r * 3 + c) * CINW + w] = base[((size_t)r * IPW + c) * CINW + w];
  int npa = 0;
#pragma unroll
  for (int t = 0; t < K; ++t) npa -= __popcll(A[t]);

  size_t orow;
  if (OPAD)
    orow = (((size_t)n * (OUT_HW + 2) + (y + 1)) * (OUT_HW + 4) + px + 1) * OW32;
  else
    orow = (((size_t)n * OUT_HW + y) * OUT_HW + px) * OW32;
  u32* out32 = (u32*)aout;
  int oc0 = split * NOC;

  u64 Wa[K], Wb[K];
  int Wa_Tx, Wa_fl, Wb_Tx, Wb_fl;

#define LDW(WB, OCX) {                                                   \
  const u64* _wr = wp + (size_t)(OCX) * K + dz;   /* dz: VGPR -> VMEM */ \
  _Pragma("unroll") for (int t = 0; t < K; ++t) WB[t] = _wr[t];          \
  int2 _tv = *(const int2*)(tf + 2 * (OCX) + 2 * dz);                    \
  WB##_Tx = _tv.x; WB##_fl = _tv.y; }

#define CMP(WB, OCJ) {                                                   \
  int s_ = 0;                                                            \
  _Pragma("unroll") for (int t = 0; t < K; ++t)                          \
    s_ += __popcll(A[t] & WB[t]);                                        \
  int val_ = (s_ << 1) + npa;                                            \
  if (Z) {                                                               \
    const u64* _zr = wz + (size_t)(OCJ) * K + dz;                        \
    _Pragma("unroll") for (int t = 0; t < K; ++t)                        \
      val_ += __popcll(A[t] & _zr[t]);                                   \
  }                                                                      \
  int tt_ = (val_ ^ WB##_fl) - WB##_Tx;                                  \
  accw |= (((u32)~tt_) >> 31) << ((OCJ) & 31); }

  LDW(Wa, oc0)
#pragma unroll
  for (int ch = 0; ch < NCH; ++ch) {
    u32 accw = 0;
    int ocb = oc0 + ch * 32;
#pragma unroll 1
    for (int jj = 0; jj < 16; ++jj) {
      int o0 = ocb + 2 * jj;
      LDW(Wb, o0 + 1)
      CMP(Wa, o0)
      LDW(Wa, o0 + 2)      // last iteration prefetches pad row (allocated)
      CMP(Wb, o0 + 1)
    }
    out32[orow + (u32)(oc0 / 32 + ch)] = accw;
  }
#undef LDW
#undef CMP
}

template <int CINW, int COUT, int STRIDE, int IN_HW, int OUT_HW, int NSPLIT, int OPAD>
__global__ __launch_bounds__(256) void bconv_vm(
    const u64* __restrict__ ain, const u64* __restrict__ wp, const u64* __restrict__ wz,
    const u32* __restrict__ flag, const int* __restrict__ tf, u64* __restrict__ aout) {
  int tid = threadIdx.x, lane = tid & 63;
  int wv = __builtin_amdgcn_readfirstlane(tid >> 6);
  int widx = blockIdx.x * 4 + wv;
  int dz;
  asm volatile("v_mov_b32 %0, 0" : "=v"(dz));
  bool anyz = (*flag != 0u);
  if (anyz)
    bconv_vm_body<CINW, COUT, STRIDE, IN_HW, OUT_HW, NSPLIT, OPAD, true>(
        ain, wp, wz, tf, aout, widx, lane, dz);
  else
    bconv_vm_body<CINW, COUT, STRIDE, IN_HW, OUT_HW, NSPLIT, OPAD, false>(
        ain, wp, wz, tf, aout, widx, lane, dz);
}

// ---------------------------------------------------------------------------
// conv5 (binarized 1x1, 192->192) + BN + ReLU + partial pool; activation
// stream via VMEM (dz) for in-order pipelining.
// ---------------------------------------------------------------------------
#define NCH5 8
__global__ __launch_bounds__(192) void bconv5_pool(
    const u64* __restrict__ ain, const u64* __restrict__ wp, const u64* __restrict__ wz,
    const u32* __restrict__ flag, const float* __restrict__ inv5, const float* __restrict__ cc5,
    float* __restrict__ partial) {
  int n = blockIdx.x / NCH5, ch = blockIdx.x % NCH5;
  int oc = threadIdx.x;
  int dz;
  asm volatile("v_mov_b32 %0, 0" : "=v"(dz));
  u64 W0 = wp[oc * 3], W1 = wp[oc * 3 + 1], W2 = wp[oc * 3 + 2];
  bool anyz = (*flag != 0u);
  float iv = inv5[oc], cb = cc5[oc];
  const u64* sb = ain + ((size_t)n * 1024 + ch * 128) * 3;
  u64 A0, A1, A2, B0, B1, B2, C0, C1, C2;
  float acc = 0.f;
#define LD5(P, a0_, a1_, a2_) { a0_ = sb[(P) * 3 + dz]; a1_ = sb[(P) * 3 + 1 + dz]; a2_ = sb[(P) * 3 + 2 + dz]; }
#define PX5(a0_, a1_, a2_) {                                                   \
  int _pa = __popcll(a0_) + __popcll(a1_) + __popcll(a2_);                     \
  int _s = __popcll(a0_ & W0) + __popcll(a1_ & W1) + __popcll(a2_ & W2);       \
  int _val = 2 * _s - _pa;                                                     \
  if (anyz) _val += __popcll(a0_ & wz[oc * 3]) + __popcll(a1_ & wz[oc * 3 + 1])\
                  + __popcll(a2_ & wz[oc * 3 + 2]);                            \
  float _b = __fadd_rn(__fmul_rn((float)_val, iv), cb);                        \
  acc += fmaxf(_b, 0.f); }
  LD5(0, A0, A1, A2); LD5(1, B0, B1, B2);
  for (int g = 0; g < 42; ++g) {
    LD5(2, C0, C1, C2); PX5(A0, A1, A2);
    LD5(3, A0, A1, A2); PX5(B0, B1, B2);
    LD5(4, B0, B1, B2); PX5(C0, C1, C2);
    sb += 9;
  }
  PX5(A0, A1, A2); PX5(B0, B1, B2);
  partial[((size_t)n * NCH5 + ch) * 192 + oc] = acc;
#undef LD5
#undef PX5
}

// ---------------------------------------------------------------------------
// Fused reduce + head (unchanged).
// ---------------------------------------------------------------------------
__global__ __launch_bounds__(192) void head2(
    const float* __restrict__ partial,
    const float* __restrict__ w6, const float* __restrict__ b6,
    const float* __restrict__ fw, const float* __restrict__ fb,
    float* __restrict__ out) {
  __shared__ float pool_s[192];
  __shared__ float h6s[12];
  __shared__ float lgs[12];
  int n = blockIdx.x, t = threadIdx.x;
  float s = 0.f;
#pragma unroll
  for (int ch = 0; ch < NCH5; ++ch) s += partial[((size_t)n * NCH5 + ch) * 192 + t];
  pool_s[t] = s;
  __syncthreads();
  if (t < 12) {
    float a = 0.f;
    for (int c = 0; c < 192; ++c) a += pool_s[c] * w6[t * 192 + c];
    h6s[t] = b6[t] + a * (1.0f / 1024.0f);
  }
  __syncthreads();
  if (t < 12) {
    float s2 = fb[t];
    for (int k = 0; k < 12; ++k) s2 += h6s[k] * fw[t * 12 + k];
    lgs[t] = s2;
  }
  __syncthreads();
  if (t == 0) {
    float mx = -1e30f;
    for (int j = 0; j < 12; ++j) mx = fmaxf(mx, lgs[j]);
    float e[12], se = 0.f;
    for (int j = 0; j < 12; ++j) { e[j] = expf(lgs[j] - mx); se += e[j]; }
    for (int j = 0; j < 12; ++j) out[n * 12 + j] = e[j] / se;
  }
}

// ---------------------------------------------------------------------------
// Launch
// ---------------------------------------------------------------------------
extern "C" void kernel_launch(void* const* d_in, const int* in_sizes, int n_in,
                              void* d_out, int out_size, void* d_ws, size_t ws_size,
                              hipStream_t stream) {
  const float* x   = (const float*)d_in[0];
  const float* w1  = (const float*)d_in[1];
  const float* b1  = (const float*)d_in[2];
  const float* w2  = (const float*)d_in[3];
  const float* w3  = (const float*)d_in[4];
  const float* w4  = (const float*)d_in[5];
  const float* w5  = (const float*)d_in[6];
  const float* w6  = (const float*)d_in[7];
  const float* b6  = (const float*)d_in[8];
  const float* fcw = (const float*)d_in[9];
  const float* fcb = (const float*)d_in[10];
  float* out = (float*)d_out;

  char* ws = (char*)d_ws;
  size_t off = 0;
  auto alloc = [&](size_t bytes) -> void* {
    void* p = ws + off;
    off += (bytes + 255) & ~(size_t)255;
    return p;
  };
  size_t xp_sz = (size_t)128 * 130 * 136 * 4;
  size_t a1_sz = (size_t)128 * 66 * 68 * 1 * 8;
  size_t a2_sz = (size_t)128 * 66 * 68 * 2 * 8;
  size_t a3_sz = (size_t)128 * 34 * 36 * 2 * 8;
  float* xpad = (float*)alloc(xp_sz);
  u64* a1p = (u64*)alloc(a1_sz);
  u64* a2p = (u64*)alloc(a2_sz);
  u64* a3p = (u64*)alloc(a3_sz);
  size_t zero_sz = xp_sz + a1_sz + a2_sz + a3_sz;
  u64* a4p = (u64*)alloc((size_t)128 * 32 * 32 * 3 * 8);
  float* partial = (float*)alloc((size_t)128 * NCH5 * 192 * 4);
  float* inv1 = (float*)alloc(64 * 4);
  float* cc1  = (float*)alloc(64 * 4);
  float* inv5 = (float*)alloc(192 * 4);
  float* cc5  = (float*)alloc(192 * 4);
  // tf/wp/wz padded by one oc row for the VM pipeline's trailing prefetch.
  int* tf2 = (int*)alloc((128 * 2 + 8) * 4);
  int* tf3 = (int*)alloc((128 * 2 + 8) * 4);
  int* tf4 = (int*)alloc((192 * 2 + 8) * 4);
  u64* wp2 = (u64*)alloc((128 * 9 + 16) * 8);
  u64* wz2 = (u64*)alloc((128 * 9 + 16) * 8);
  u64* wp3 = (u64*)alloc((128 * 18 + 32) * 8);
  u64* wz3 = (u64*)alloc((128 * 18 + 32) * 8);
  u64* wp4 = (u64*)alloc((192 * 18 + 32) * 8);
  u64* wz4 = (u64*)alloc((192 * 18 + 32) * 8);
  u64* wp5 = (u64*)alloc(192 * 1 * 3 * 8);
  u64* wz5 = (u64*)alloc(192 * 1 * 3 * 8);
  u32* flags = (u32*)alloc(4 * sizeof(u32));
  (void)ws_size; (void)n_in; (void)in_sizes; (void)out_size;

  hipMemsetAsync(xpad, 0, zero_sz, stream);
  hipMemsetAsync(flags, 0, 4 * sizeof(u32), stream);

  PrepArgs pa;
  for (int l = 0; l < 5; ++l) {
    pa.bng[l] = (const float*)d_in[11 + 4 * l + 0];
    pa.bnb[l] = (const float*)d_in[11 + 4 * l + 1];
    pa.bnm[l] = (const float*)d_in[11 + 4 * l + 2];
    pa.bnv[l] = (const float*)d_in[11 + 4 * l + 3];
  }
  pa.inv1 = inv1; pa.cc1 = cc1; pa.inv5 = inv5; pa.cc5 = cc5;
  pa.tf[0] = tf2; pa.tf[1] = tf3; pa.tf[2] = tf4;
  pa.w[0] = w2; pa.w[1] = w3; pa.w[2] = w4; pa.w[3] = w5;
  pa.wp[0] = wp2; pa.wp[1] = wp3; pa.wp[2] = wp4; pa.wp[3] = wp5;
  pa.wz[0] = wz2; pa.wz[1] = wz3; pa.wz[2] = wz4; pa.wz[3] = wz5;
  pa.flags = flags;
  prep_all<<<32, 256, 0, stream>>>(pa);

  pad_x<<<(128 * 128 * 128) / 256, 256, 0, stream>>>(x, xpad);

  conv1_px<<<2048, 256, 0, stream>>>(xpad, w1, b1, inv1, cc1, a1p);

  // conv2 A/B split: images 0..63 via SMEM baseline, 64..127 via VMEM pipe.
  bconv_sm<1, 128, 1, 64, 64, 1, 1, 1><<<1024, 256, 0, stream>>>(
      a1p, wp2, wz2, flags + 0, tf2, a2p);
  bconv_vm<1, 128, 1, 64, 64, 1, 1><<<1024, 256, 0, stream>>>(
      a1p + (size_t)64 * 66 * 68, wp2, wz2, flags + 0, tf2,
      a2p + (size_t)64 * 66 * 68 * 2);

  // conv3: VMEM pipe, 128->128, 64->32 s2, padded out. 4096 waves.
  bconv_vm<2, 128, 2, 64, 32, 2, 1><<<1024, 256, 0, stream>>>(
      a2p, wp3, wz3, flags + 1, tf3, a3p);

  // conv4: VMEM pipe, 128->192, 32x32 s1, dense out. 4096 waves.
  bconv_vm<2, 192, 1, 32, 32, 2, 0><<<1024, 256, 0, stream>>>(
      a3p, wp4, wz4, flags + 2, tf4, a4p);

  bconv5_pool<<<128 * NCH5, 192, 0, stream>>>(a4p, wp5, wz5, flags + 3, inv5, cc5, partial);

  head2<<<128, 192, 0, stream>>>(partial, w6, b6, fcw, fcb, out);
}

// Round 11
// 288.309 us; speedup vs baseline: 1.5067x; 1.5067x over previous
//
#include <hip/hip_runtime.h>
#include <cstdint>

using u64 = unsigned long long;
using u32 = unsigned int;

// ---------------------------------------------------------------------------
// Fused prep: BN constants + exact integer thresholds (layers 2-4) + packing.
// ---------------------------------------------------------------------------
struct PrepArgs {
  const float* bng[5]; const float* bnb[5]; const float* bnm[5]; const float* bnv[5];
  float* inv1; float* cc1; float* inv5; float* cc5;
  int* thr[3]; int* flp[3];
  const float* w[4];
  u64* wp[4]; u64* wz[4];
  u32* flags;
};

__global__ __launch_bounds__(256) void prep_all(PrepArgs a) {
  int i = blockIdx.x * 256 + threadIdx.x;
  if (i < 704) {
    const int off[6] = {0, 64, 192, 320, 512, 704};
    int l = 0;
    while (i >= off[l + 1]) ++l;
    int c = i - off[l];
    float iv = __fdiv_rn(a.bng[l][c], __fsqrt_rn(__fadd_rn(a.bnv[l][c], 1e-5f)));
    float cb = __fsub_rn(a.bnb[l][c], __fmul_rn(a.bnm[l][c], iv));
    if (l == 0) { a.inv1[c] = iv; a.cc1[c] = cb; }
    else if (l == 4) { a.inv5[c] = iv; a.cc5[c] = cb; }
    else {
      auto pred = [&](int v_) {
        return __fadd_rn(__fmul_rn((float)v_, iv), cb) > 0.f;
      };
      int Tx, fl;
      if (iv == 0.f) { Tx = pred(0) ? -100000 : 100000; fl = 0; }
      else if (iv > 0.f) {
        if (pred(-2048)) { Tx = -100000; fl = 0; }
        else if (!pred(2048)) { Tx = 100000; fl = 0; }
        else {
          int lo = -2048, hi = 2048;
          while (hi - lo > 1) { int md = (lo + hi) >> 1; if (pred(md)) hi = md; else lo = md; }
          Tx = hi; fl = 0;   // bit = val >= Tx
        }
      } else {
        if (pred(2048)) { Tx = -100000; fl = -1; }
        else if (!pred(-2048)) { Tx = 100000; fl = -1; }
        else {
          int lo = -2048, hi = 2048;
          while (hi - lo > 1) { int md = (lo + hi) >> 1; if (pred(md)) lo = md; else hi = md; }
          Tx = lo ^ -1; fl = -1;   // bit = val <= lo  <=>  (val^-1) >= (~lo)
        }
      }
      a.thr[l - 1][c] = Tx; a.flp[l - 1][c] = fl;
    }
    return;
  }
  int j = i - 704;
  if (j >= 7488) return;
  const int poff[5] = {0, 1152, 3456, 6912, 7488};
  const int ICt[4] = {64, 128, 128, 192};
  const int Kt[4]  = {9, 9, 9, 1};
  const int Wt[4]  = {1, 2, 2, 3};
  int l = 0;
  while (j >= poff[l + 1]) ++l;
  int idx = j - poff[l];
  int W = Wt[l], K = Kt[l], IC = ICt[l];
  int wi = idx % W;
  int rest = idx / W;
  int t = rest % K;
  int oc = rest / K;
  u64 p = 0, z = 0;
  int icbase = wi * 64;
  int nb = IC - icbase; if (nb > 64) nb = 64;
  const float* w = a.w[l];
  for (int b = 0; b < nb; ++b) {
    float f = w[((size_t)oc * IC + (icbase + b)) * K + t];
    if (f > 0.f) p |= (1ull << b);
    else if (f == 0.f) z |= (1ull << b);
  }
  a.wp[l][idx] = p;
  a.wz[l][idx] = z;
  if (z) atomicOr(a.flags + l, 1u);
}

// ---------------------------------------------------------------------------
// Pad fp32 input into [n][130][136] (zero borders; data at row+1, col+1).
// ---------------------------------------------------------------------------
__global__ __launch_bounds__(256) void pad_x(const float* __restrict__ x,
                                             float* __restrict__ xpad) {
  int idx = blockIdx.x * 256 + threadIdx.x;   // 128*128*128
  int c = idx & 127, r = (idx >> 7) & 127, n = idx >> 14;
  xpad[((size_t)n * 130 + r + 1) * 136 + c + 1] = x[idx];
}

// ---------------------------------------------------------------------------
// conv1 (R6 version, verified): fp32 1->64ch 3x3 s2 + bias + BN threshold ->
// padded bit-pack. lane = channel; activations via scalar ring.
// ---------------------------------------------------------------------------
__global__ __launch_bounds__(256) void conv1_bin(
    const float* __restrict__ xpad, const float* __restrict__ w1, const float* __restrict__ b1,
    const float* __restrict__ inv1, const float* __restrict__ cc1,
    u64* __restrict__ a1p) {
  int tid = threadIdx.x, lane = tid & 63;
  int rb = __builtin_amdgcn_readfirstlane(tid >> 6);
  int blk = blockIdx.x;                // 128*16
  int y = (blk % 16) * 4 + rb;
  int n = blk / 16;
  float W[9];
#pragma unroll
  for (int t = 0; t < 9; ++t) W[t] = w1[lane * 9 + t];
  float bias = b1[lane], iv = inv1[lane], cb = cc1[lane];
  const float* sb = xpad + ((size_t)n * 130 + 2 * y) * 136;
  float A[12], B[12], C[12];
  u64 rowm = 0;
  int xb = 0;

#define FLD(BUF, POFF)                                     \
  _Pragma("unroll") for (int _r = 0; _r < 3; ++_r)         \
  _Pragma("unroll") for (int _j = 0; _j < 4; ++_j)         \
    BUF[_r * 4 + _j] = sb[_r * 136 + (POFF) + _j];
#define FPX(XO, B0F, C0, B1F, C1, B2F, C2) {                          \
  float acc = 0.f;                                                    \
  _Pragma("unroll") for (int _r = 0; _r < 3; ++_r)                    \
    acc += B0F[_r * 4 + (C0)] * W[_r * 3 + 0]                         \
         + B1F[_r * 4 + (C1)] * W[_r * 3 + 1]                         \
         + B2F[_r * 4 + (C2)] * W[_r * 3 + 2];                        \
  float h = __fadd_rn(acc, bias);                                     \
  float bnv = __fadd_rn(__fmul_rn(h, iv), cb);                        \
  u64 _m = __ballot(bnv > 0.f);                                       \
  rowm = (lane == (XO)) ? _m : rowm; }
#define FSTEP(BA, BB, BC, POFF, XB)  \
  FLD(BC, (POFF) + 8);               \
  FPX((XB), BA, 0, BA, 1, BA, 2);    \
  FPX((XB) + 1, BA, 2, BA, 3, BB, 0);

  FLD(A, 0); FLD(B, 4);
  for (int g = 0; g < 10; ++g) {
    FSTEP(A, B, C, 0, xb);
    FSTEP(B, C, A, 4, xb + 2);
    FSTEP(C, A, B, 8, xb + 4);
    sb += 12; xb += 6;
  }
  FSTEP(A, B, C, 0, xb);
  FSTEP(B, C, A, 4, xb + 2);
  a1p[((size_t)n * 66 + (y + 1)) * 68 + lane + 1] = rowm;
#undef FLD
#undef FPX
#undef FSTEP
}

// ---------------------------------------------------------------------------
// Binarized 3x3 conv (R6 structure + OCPL merge). lane covers OCPL output
// channels (oc = q*64+lane), all weights in VGPRs; activation columns in a
// 3-buffer scalar ring (wave-uniform s_loads, SALU popcounts). One wave per
// output row handles ALL channels -> stream fetched once per row, and OCPL×
// more VALU between fetches hides the SMEM latency.
// ---------------------------------------------------------------------------
template <int CINW, int OCPL, int STRIDE, int IN_HW, int OUT_HW, int RPB, int OPAD>
__global__ __launch_bounds__(64 * RPB) void bconv(
    const u64* __restrict__ ain, const u64* __restrict__ wp, const u64* __restrict__ wz,
    const u32* __restrict__ flag, const int* __restrict__ thr, const int* __restrict__ flp,
    u64* __restrict__ aout) {
  constexpr int IPW = IN_HW + 4;
  constexpr int K = 9 * CINW;
  int tid = threadIdx.x;
  int lane = tid & 63;
  int wv = __builtin_amdgcn_readfirstlane(tid >> 6);
  int blk = blockIdx.x;
  constexpr int BPI = OUT_HW / RPB;
  int y = (blk % BPI) * RPB + wv;
  int n = blk / BPI;

  u64 W[OCPL * K];
  int Tx[OCPL], flip[OCPL];
#pragma unroll
  for (int q = 0; q < OCPL; ++q) {
    int oc = q * 64 + lane;
#pragma unroll
    for (int t = 0; t < K; ++t) W[q * K + t] = wp[(size_t)oc * K + t];
    Tx[q] = thr[oc]; flip[q] = flp[oc];
  }
  bool anyz = (*flag != 0u);

  const u64* sb = ain + ((size_t)n * (IN_HW + 2) + STRIDE * y) * IPW * CINW;

  u64 A[6 * CINW], B[6 * CINW], C[6 * CINW];
  int pA0 = 0, pA1 = 0, pB0 = 0, pB1 = 0, pC0 = 0, pC1 = 0;
  u64 rowmL[OCPL];
#pragma unroll
  for (int q = 0; q < OCPL; ++q) rowmL[q] = 0;
  int xb = 0;

#define LDB(BUF, POFF)                                      \
  _Pragma("unroll") for (int _r = 0; _r < 3; ++_r)          \
  _Pragma("unroll") for (int _j = 0; _j < 2 * CINW; ++_j)   \
    BUF[_r * 2 * CINW + _j] = sb[((size_t)_r * IPW + (POFF)) * CINW + _j];
#define PCP(BUF, p0, p1) {                                  \
  int _q0 = 0, _q1 = 0;                                     \
  _Pragma("unroll") for (int _r = 0; _r < 3; ++_r)          \
  _Pragma("unroll") for (int _w = 0; _w < CINW; ++_w) {     \
    _q0 += __popcll(BUF[_r * 2 * CINW + _w]);               \
    _q1 += __popcll(BUF[_r * 2 * CINW + CINW + _w]); }      \
  (p0) = _q0; (p1) = _q1; }
#define PIX(XO, BA, CA, BB, CB, BC, CC, PATOT) {                                          \
  _Pragma("unroll") for (int _q = 0; _q < OCPL; ++_q) {                                   \
    int _s = 0;                                                                           \
    _Pragma("unroll") for (int _r = 0; _r < 3; ++_r)                                      \
    _Pragma("unroll") for (int _w = 0; _w < CINW; ++_w) {                                 \
      _s += __popcll(BA[(_r * 2 + (CA)) * CINW + _w] & W[_q * K + (_r * 3 + 0) * CINW + _w]); \
      _s += __popcll(BB[(_r * 2 + (CB)) * CINW + _w] & W[_q * K + (_r * 3 + 1) * CINW + _w]); \
      _s += __popcll(BC[(_r * 2 + (CC)) * CINW + _w] & W[_q * K + (_r * 3 + 2) * CINW + _w]); } \
    int _val = 2 * _s - (PATOT);                                                          \
    if (anyz) {                                                                           \
      const u64* _zr = wz + (size_t)(_q * 64 + lane) * K;                                 \
      for (int _r = 0; _r < 3; ++_r) for (int _w = 0; _w < CINW; ++_w) {                  \
        _val += __popcll(BA[(_r * 2 + (CA)) * CINW + _w] & _zr[(_r * 3 + 0) * CINW + _w]);\
        _val += __popcll(BB[(_r * 2 + (CB)) * CINW + _w] & _zr[(_r * 3 + 1) * CINW + _w]);\
        _val += __popcll(BC[(_r * 2 + (CC)) * CINW + _w] & _zr[(_r * 3 + 2) * CINW + _w]); } } \
    u64 _m = __ballot((_val ^ flip[_q]) >= Tx[_q]);                                       \
    rowmL[_q] = (lane == (XO)) ? _m : rowmL[_q]; } }
#define STEP1(BA, pa0, pa1, BB, pb0, pb1, BC, POFF, XB)         \
  LDB(BC, (POFF) + 4);                                          \
  PCP(BB, pb0, pb1);                                            \
  PIX((XB), BA, 0, BA, 1, BB, 0, (pa0) + (pa1) + (pb0));        \
  PIX((XB) + 1, BA, 1, BB, 0, BB, 1, (pa1) + (pb0) + (pb1));
#define STEP2(BA, pa0, pa1, BB, pb0, pb1, BC, POFF, XB)         \
  LDB(BC, (POFF) + 4);                                          \
  PCP(BB, pb0, pb1);                                            \
  PIX((XB), BA, 0, BA, 1, BB, 0, (pa0) + (pa1) + (pb0));

  LDB(A, 0); LDB(B, 2);
  PCP(A, pA0, pA1);
  constexpr int NSTEP = (STRIDE == 1) ? OUT_HW / 2 : OUT_HW;
  constexpr int NG = NSTEP / 3;
  constexpr int NT = NSTEP % 3;
  for (int g = 0; g < NG; ++g) {
    if constexpr (STRIDE == 1) {
      STEP1(A, pA0, pA1, B, pB0, pB1, C, 0, xb);
      STEP1(B, pB0, pB1, C, pC0, pC1, A, 2, xb + 2);
      STEP1(C, pC0, pC1, A, pA0, pA1, B, 4, xb + 4);
      xb += 6;
    } else {
      STEP2(A, pA0, pA1, B, pB0, pB1, C, 0, xb);
      STEP2(B, pB0, pB1, C, pC0, pC1, A, 2, xb + 1);
      STEP2(C, pC0, pC1, A, pA0, pA1, B, 4, xb + 2);
      xb += 3;
    }
    sb += 6 * CINW;
  }
  if constexpr (NT >= 1) {
    if constexpr (STRIDE == 1) { STEP1(A, pA0, pA1, B, pB0, pB1, C, 0, xb) }
    else { STEP2(A, pA0, pA1, B, pB0, pB1, C, 0, xb) }
  }
  if constexpr (NT >= 2) {
    if constexpr (STRIDE == 1) { STEP1(B, pB0, pB1, C, pC0, pC1, A, 2, xb + 2) }
    else { STEP2(B, pB0, pB1, C, pC0, pC1, A, 2, xb + 1) }
  }
#undef LDB
#undef PCP
#undef PIX
#undef STEP1
#undef STEP2

  if (OUT_HW == 64 || lane < OUT_HW) {
#pragma unroll
    for (int q = 0; q < OCPL; ++q) {
      if constexpr (OPAD)
        aout[(((size_t)n * (OUT_HW + 2) + (y + 1)) * (OUT_HW + 4) + lane + 1) * OCPL + q] = rowmL[q];
      else
        aout[(((size_t)n * OUT_HW + y) * OUT_HW + lane) * OCPL + q] = rowmL[q];
    }
  }
}

// ---------------------------------------------------------------------------
// conv5 (R6 version): binarized 1x1 + BN + ReLU + partial pool.
// ---------------------------------------------------------------------------
#define NCH5 8
__global__ __launch_bounds__(192) void bconv5_pool(
    const u64* __restrict__ ain, const u64* __restrict__ wp, const u64* __restrict__ wz,
    const u32* __restrict__ flag, const float* __restrict__ inv5, const float* __restrict__ cc5,
    float* __restrict__ partial) {
  int n = blockIdx.x / NCH5, ch = blockIdx.x % NCH5;
  int oc = threadIdx.x;
  u64 W0 = wp[oc * 3], W1 = wp[oc * 3 + 1], W2 = wp[oc * 3 + 2];
  bool anyz = (*flag != 0u);
  float iv = inv5[oc], cb = cc5[oc];
  const u64* sb = ain + ((size_t)n * 1024 + ch * 128) * 3;
  u64 A0, A1, A2, B0, B1, B2, C0, C1, C2;
  float acc = 0.f;
#define LD5(P, a0_, a1_, a2_) { a0_ = sb[(P) * 3]; a1_ = sb[(P) * 3 + 1]; a2_ = sb[(P) * 3 + 2]; }
#define PX5(a0_, a1_, a2_) {                                                   \
  int _pa = __popcll(a0_) + __popcll(a1_) + __popcll(a2_);                     \
  int _s = __popcll(a0_ & W0) + __popcll(a1_ & W1) + __popcll(a2_ & W2);       \
  int _val = 2 * _s - _pa;                                                     \
  if (anyz) _val += __popcll(a0_ & wz[oc * 3]) + __popcll(a1_ & wz[oc * 3 + 1])\
                  + __popcll(a2_ & wz[oc * 3 + 2]);                            \
  float _b = __fadd_rn(__fmul_rn((float)_val, iv), cb);                        \
  acc += fmaxf(_b, 0.f); }
  LD5(0, A0, A1, A2); LD5(1, B0, B1, B2);
  for (int g = 0; g < 42; ++g) {
    LD5(2, C0, C1, C2); PX5(A0, A1, A2);
    LD5(3, A0, A1, A2); PX5(B0, B1, B2);
    LD5(4, B0, B1, B2); PX5(C0, C1, C2);
    sb += 9;
  }
  PX5(A0, A1, A2); PX5(B0, B1, B2);
  partial[((size_t)n * NCH5 + ch) * 192 + oc] = acc;
#undef LD5
#undef PX5
}

// ---------------------------------------------------------------------------
// Fused reduce + head (R6 version).
// ---------------------------------------------------------------------------
__global__ __launch_bounds__(192) void head2(
    const float* __restrict__ partial,
    const float* __restrict__ w6, const float* __restrict__ b6,
    const float* __restrict__ fw, const float* __restrict__ fb,
    float* __restrict__ out) {
  __shared__ float pool_s[192];
  __shared__ float h6s[12];
  __shared__ float lgs[12];
  int n = blockIdx.x, t = threadIdx.x;
  float s = 0.f;
#pragma unroll
  for (int ch = 0; ch < NCH5; ++ch) s += partial[((size_t)n * NCH5 + ch) * 192 + t];
  pool_s[t] = s;
  __syncthreads();
  if (t < 12) {
    float a = 0.f;
    for (int c = 0; c < 192; ++c) a += pool_s[c] * w6[t * 192 + c];
    h6s[t] = b6[t] + a * (1.0f / 1024.0f);
  }
  __syncthreads();
  if (t < 12) {
    float s2 = fb[t];
    for (int k = 0; k < 12; ++k) s2 += h6s[k] * fw[t * 12 + k];
    lgs[t] = s2;
  }
  __syncthreads();
  if (t == 0) {
    float mx = -1e30f;
    for (int j = 0; j < 12; ++j) mx = fmaxf(mx, lgs[j]);
    float e[12], se = 0.f;
    for (int j = 0; j < 12; ++j) { e[j] = expf(lgs[j] - mx); se += e[j]; }
    for (int j = 0; j < 12; ++j) out[n * 12 + j] = e[j] / se;
  }
}

// ---------------------------------------------------------------------------
// Launch
// ---------------------------------------------------------------------------
extern "C" void kernel_launch(void* const* d_in, const int* in_sizes, int n_in,
                              void* d_out, int out_size, void* d_ws, size_t ws_size,
                              hipStream_t stream) {
  const float* x   = (const float*)d_in[0];
  const float* w1  = (const float*)d_in[1];
  const float* b1  = (const float*)d_in[2];
  const float* w2  = (const float*)d_in[3];
  const float* w3  = (const float*)d_in[4];
  const float* w4  = (const float*)d_in[5];
  const float* w5  = (const float*)d_in[6];
  const float* w6  = (const float*)d_in[7];
  const float* b6  = (const float*)d_in[8];
  const float* fcw = (const float*)d_in[9];
  const float* fcb = (const float*)d_in[10];
  float* out = (float*)d_out;

  char* ws = (char*)d_ws;
  size_t off = 0;
  auto alloc = [&](size_t bytes) -> void* {
    void* p = ws + off;
    off += (bytes + 255) & ~(size_t)255;
    return p;
  };
  size_t xp_sz = (size_t)128 * 130 * 136 * 4;
  size_t a1_sz = (size_t)128 * 66 * 68 * 1 * 8;
  size_t a2_sz = (size_t)128 * 66 * 68 * 2 * 8;
  size_t a3_sz = (size_t)128 * 34 * 36 * 2 * 8;
  float* xpad = (float*)alloc(xp_sz);
  u64* a1p = (u64*)alloc(a1_sz);
  u64* a2p = (u64*)alloc(a2_sz);
  u64* a3p = (u64*)alloc(a3_sz);
  size_t zero_sz = xp_sz + a1_sz + a2_sz + a3_sz;
  u64* a4p = (u64*)alloc((size_t)128 * 32 * 32 * 3 * 8);
  float* partial = (float*)alloc((size_t)128 * NCH5 * 192 * 4);
  float* inv1 = (float*)alloc(64 * 4);
  float* cc1  = (float*)alloc(64 * 4);
  float* inv5 = (float*)alloc(192 * 4);
  float* cc5  = (float*)alloc(192 * 4);
  int* thr2 = (int*)alloc(128 * 4); int* flp2 = (int*)alloc(128 * 4);
  int* thr3 = (int*)alloc(128 * 4); int* flp3 = (int*)alloc(128 * 4);
  int* thr4 = (int*)alloc(192 * 4); int* flp4 = (int*)alloc(192 * 4);
  u64* wp2 = (u64*)alloc(128 * 9 * 1 * 8);
  u64* wz2 = (u64*)alloc(128 * 9 * 1 * 8);
  u64* wp3 = (u64*)alloc(128 * 9 * 2 * 8);
  u64* wz3 = (u64*)alloc(128 * 9 * 2 * 8);
  u64* wp4 = (u64*)alloc(192 * 9 * 2 * 8);
  u64* wz4 = (u64*)alloc(192 * 9 * 2 * 8);
  u64* wp5 = (u64*)alloc(192 * 1 * 3 * 8);
  u64* wz5 = (u64*)alloc(192 * 1 * 3 * 8);
  u32* flags = (u32*)alloc(4 * sizeof(u32));
  (void)ws_size; (void)n_in; (void)in_sizes; (void)out_size;

  hipMemsetAsync(xpad, 0, zero_sz, stream);
  hipMemsetAsync(flags, 0, 4 * sizeof(u32), stream);

  PrepArgs pa;
  for (int l = 0; l < 5; ++l) {
    pa.bng[l] = (const float*)d_in[11 + 4 * l + 0];
    pa.bnb[l] = (const float*)d_in[11 + 4 * l + 1];
    pa.bnm[l] = (const float*)d_in[11 + 4 * l + 2];
    pa.bnv[l] = (const float*)d_in[11 + 4 * l + 3];
  }
  pa.inv1 = inv1; pa.cc1 = cc1; pa.inv5 = inv5; pa.cc5 = cc5;
  pa.thr[0] = thr2; pa.flp[0] = flp2;
  pa.thr[1] = thr3; pa.flp[1] = flp3;
  pa.thr[2] = thr4; pa.flp[2] = flp4;
  pa.w[0] = w2; pa.w[1] = w3; pa.w[2] = w4; pa.w[3] = w5;
  pa.wp[0] = wp2; pa.wp[1] = wp3; pa.wp[2] = wp4; pa.wp[3] = wp5;
  pa.wz[0] = wz2; pa.wz[1] = wz3; pa.wz[2] = wz4; pa.wz[3] = wz5;
  pa.flags = flags;
  prep_all<<<32, 256, 0, stream>>>(pa);

  pad_x<<<(128 * 128 * 128) / 256, 256, 0, stream>>>(x, xpad);

  // conv1: 4 rows per 256-thread block
  conv1_bin<<<128 * 16, 256, 0, stream>>>(xpad, w1, b1, inv1, cc1, a1p);

  // conv2: 64ch(1w)->128ch, 64x64, s1. OCPL=2 (one wave = all 128 oc), 4 rows/block.
  bconv<1, 2, 1, 64, 64, 4, 1><<<128 * 16, 256, 0, stream>>>(
      a1p, wp2, wz2, flags + 0, thr2, flp2, a2p);

  // conv3: 128ch(2w)->128ch, 64->32, s2. OCPL=2, 4 rows/block.
  bconv<2, 2, 2, 64, 32, 4, 1><<<128 * 8, 256, 0, stream>>>(
      a2p, wp3, wz3, flags + 1, thr3, flp3, a3p);

  // conv4: 128ch(2w)->192ch, 32x32, s1. OCPL=3, 4 rows/block.
  bconv<2, 3, 1, 32, 32, 4, 0><<<128 * 8, 256, 0, stream>>>(
      a3p, wp4, wz4, flags + 2, thr4, flp4, a4p);

  // conv5 (1x1) + bn5 + relu + partial sums
  bconv5_pool<<<128 * NCH5, 192, 0, stream>>>(a4p, wp5, wz5, flags + 3, inv5, cc5, partial);

  // fused reduce + conv6 + fc + softmax
  head2<<<128, 192, 0, stream>>>(partial, w6, b6, fcw, fcb, out);
}